// Round 7
// baseline (358.316 us; speedup 1.0000x reference)
//
#include <hip/hip_runtime.h>
#include <hip/hip_bf16.h>
#include <cstdint>

#define H 1024
#define BSZ 4
#define LSEQ 2048
#define M_TOT (BSZ*LSEQ)   // 8192
#define NCH 64             // L-chunks for the delta scan (32 rows each)
#define LCH (LSEQ/NCH)     // 32
#define NBLK 512           // fused-kernel grid; co-residency guaranteed (>=2/CU)

typedef __attribute__((ext_vector_type(4))) float  f32x4;
typedef __attribute__((ext_vector_type(2))) float  f32x2;
typedef __attribute__((ext_vector_type(8))) __bf16 bf16x8;
typedef __attribute__((ext_vector_type(4))) __bf16 bf16x4;
typedef __attribute__((ext_vector_type(2))) __bf16 bf16x2;

typedef __attribute__((address_space(1))) unsigned int as1_u32;
typedef __attribute__((address_space(3))) unsigned int as3_u32;

__device__ __forceinline__ void gld_lds16(const void* g, const void* l) {
    as1_u32* gp = reinterpret_cast<as1_u32*>((uintptr_t)g);
    as3_u32* lp = reinterpret_cast<as3_u32*>((uint32_t)(uintptr_t)l);
    __builtin_amdgcn_global_load_lds(gp, lp, 16, 0, 0);
}

__device__ __forceinline__ float softplus_fast(float f) {
    return fmaxf(f, 0.f) + __logf(1.f + __expf(-fabsf(f)));
}

// DIY grid barrier: monotone counter, agent-scope release add + acquire fence.
// Safe because all NBLK blocks are co-resident (capacity >= 2 blocks/CU by
// construction: regs capped via launch_bounds, LDS 34816*2 < 160K) and no
// block waits on anything before arriving.
__device__ __forceinline__ void grid_bar(unsigned* cnt, unsigned target) {
    __syncthreads();                       // all waves drained (vmcnt/lgkmcnt 0)
    if (threadIdx.x == 0) {
        __hip_atomic_fetch_add(cnt, 1u, __ATOMIC_RELEASE,
                               __HIP_MEMORY_SCOPE_AGENT);
        while (__hip_atomic_load(cnt, __ATOMIC_RELAXED,
                                 __HIP_MEMORY_SCOPE_AGENT) < target)
            __builtin_amdgcn_s_sleep(2);
    }
    __syncthreads();
    __builtin_amdgcn_fence(__ATOMIC_ACQUIRE, "agent");   // L1 inv / L2 sync
}

// 4x4 MFMA fragment compute from one LDS buffer (XOR-swizzled granules).
__device__ __forceinline__ void mfma_tile(const __bf16* base, const int* aoff,
                                          const int* boff, f32x4 (&acc)[4][4]) {
    bf16x8 af[4], bf[4];
#pragma unroll
    for (int i = 0; i < 4; ++i) af[i] = *(const bf16x8*)(base + aoff[i]);
#pragma unroll
    for (int j = 0; j < 4; ++j) bf[j] = *(const bf16x8*)(base + boff[j]);
#pragma unroll
    for (int i = 0; i < 4; ++i)
#pragma unroll
        for (int j = 0; j < 4; ++j)
            acc[i][j] = __builtin_amdgcn_mfma_f32_16x16x32_bf16(
                af[i], bf[j], acc[i][j], 0, 0, 0);
}

// Wfuse staging: fp32 Wd (A, coalesced-ish) and fp32 Wp transposed-scatter (B),
// converted in-register to bf16, written into the same XOR-granule layout.
__device__ __forceinline__ void stage_wfuse(__bf16* base,
        const float* __restrict__ Wd, const float* __restrict__ Wp,
        int row0f, int col0f, int kt, int tid) {
    {   // A: Wd[row0f+arow][kt*32 + ahalf*16 .. +16)
        const int arow = tid & 127, ahalf = tid >> 7;
        const float* ap = Wd + (size_t)(row0f + arow)*1024 + kt*32 + ahalf*16;
        f32x4 v0 = *(const f32x4*)(ap);
        f32x4 v1 = *(const f32x4*)(ap + 4);
        f32x4 v2 = *(const f32x4*)(ap + 8);
        f32x4 v3 = *(const f32x4*)(ap + 12);
        bf16x8 g0 = {(__bf16)v0[0],(__bf16)v0[1],(__bf16)v0[2],(__bf16)v0[3],
                     (__bf16)v1[0],(__bf16)v1[1],(__bf16)v1[2],(__bf16)v1[3]};
        bf16x8 g1 = {(__bf16)v2[0],(__bf16)v2[1],(__bf16)v2[2],(__bf16)v2[3],
                     (__bf16)v3[0],(__bf16)v3[1],(__bf16)v3[2],(__bf16)v3[3]};
        const int swz = (arow >> 1) & 3;
        *(bf16x8*)(base + (arow*4 + ((ahalf*2    ) ^ swz))*8) = g0;
        *(bf16x8*)(base + (arow*4 + ((ahalf*2 + 1) ^ swz))*8) = g1;
    }
    {   // B[h'][k] = Wp[kt*32+k][col0f+h']  (transpose scatter, 64 blocks only)
        const int bk = tid >> 3, bgrp = tid & 7;
        const float* bp = Wp + (size_t)(kt*32 + bk)*1024 + col0f + bgrp*16;
        float wv[16];
#pragma unroll
        for (int q = 0; q < 4; ++q) {
            f32x4 w = *(const f32x4*)(bp + q*4);
            wv[q*4+0]=w[0]; wv[q*4+1]=w[1]; wv[q*4+2]=w[2]; wv[q*4+3]=w[3];
        }
        const int ko = bk >> 3, ke = bk & 7;
#pragma unroll
        for (int q = 0; q < 16; ++q) {
            const int hp = bgrp*16 + q;
            base[4096 + (hp*4 + (ko ^ ((hp>>1)&3)))*8 + ke] = (__bf16)wv[q];
        }
    }
}

__global__ __launch_bounds__(256, 3) void fused(
    const float* __restrict__ x,  const float* __restrict__ Wp,
    const float* __restrict__ Av, const float* __restrict__ Bv,
    const float* __restrict__ Dv, const float* __restrict__ Wd,
    const float* __restrict__ bd,
    __bf16* __restrict__ xb,   __bf16* __restrict__ Wpb,
    __bf16* __restrict__ resb, __bf16* __restrict__ db,
    float* __restrict__ pD, float* __restrict__ pUp, float* __restrict__ pCp,
    unsigned* __restrict__ cnt, float* __restrict__ out)
{
    __shared__ __align__(16) __bf16 lds[17408];   // 2x(A4096|B4096) / seg1 tile

    const int tid  = threadIdx.x;
    const int bid  = blockIdx.x;
    const int lane = tid & 63;
    const int wid  = tid >> 6;
    const int wr   = (wid >> 1) * 64;
    const int wc   = (wid & 1) * 64;
    const int l15  = lane & 15;
    const int quad = lane >> 4;
    const int sw   = (l15 >> 1) & 3;
    int aoff[4], boff[4];
#pragma unroll
    for (int i = 0; i < 4; ++i) {
        aoff[i] =        ((wr + i*16 + l15) * 4 + (quad ^ sw)) * 8;
        boff[i] = 4096 + ((wc + i*16 + l15) * 4 + (quad ^ sw)) * 8;
    }
    const int srow = lane >> 2;
    const int soct = (lane & 3) ^ ((lane >> 3) & 3);

    // ================= Phase 0: Wfuse GEMM (0..63) || casts (64..511) ======
    if (bid < 64) {
        // Wfuse = Wd @ Wp1 -> Wpb rows 0..1023  (fp32 inputs, no dependency)
        const int row0f = (bid >> 3) * 128;
        const int col0f = (bid & 7) * 128;
        f32x4 acc[4][4] = {};
        stage_wfuse(lds, Wd, Wp, row0f, col0f, 0, tid);
#pragma unroll 2
        for (int kt = 0; kt < 32; ++kt) {
            __syncthreads();
            if (kt + 1 < 32)
                stage_wfuse(lds + ((kt+1)&1)*8192, Wd, Wp, row0f, col0f, kt+1, tid);
            mfma_tile(lds + (kt&1)*8192, aoff, boff, acc);
        }
        const int colb = col0f + wc + l15;
        const int rowb = row0f + wr + quad*4;
#pragma unroll
        for (int i = 0; i < 4; ++i)
#pragma unroll
            for (int j = 0; j < 4; ++j) {
                const int col = colb + j*16;
#pragma unroll
                for (int r = 0; r < 4; ++r)
                    Wpb[(size_t)(rowb + i*16 + r) * H + col] = (__bf16)acc[i][j][r];
            }
    } else {
        // casts: x -> xb (8192 tasks), Wp rows 2048..4095 -> Wpb rows 1024..3071
        for (int task = bid - 64; task < 10240; task += 448) {
            const f32x4* src; __bf16* dst; int si, di;
            if (task < 8192) {
                int i = task*256 + tid;
                src = (const f32x4*)x;  si = i; dst = xb;  di = i;
            } else {
                int j = (task - 8192)*256 + tid;
                int row = j >> 8, cf = j & 255;
                src = (const f32x4*)Wp; si = (2048 + row)*256 + cf;
                dst = Wpb; di = (1024 + row)*256 + cf;
            }
            f32x4 v = src[si];
            bf16x4 o = { (__bf16)v[0], (__bf16)v[1], (__bf16)v[2], (__bf16)v[3] };
            *(bf16x4*)(dst + (size_t)di*4) = o;
        }
    }

    grid_bar(cnt, NBLK);

    // ================= Phase 1: big GEMM [8192,1024]@[3072,1024]^T =========
    for (int task = bid; task < 1536; task += NBLK) {
        const int cx = task / 64;          // 0..23 (64 consecutive bids share B)
        const int ry = task % 64;
        const int row0 = ry * 128;
        const int col0 = cx * 128;
        __syncthreads();                   // lds free from previous use

        const __bf16* ag0 = xb  + (size_t)(row0 + (wid    )*16 + srow)*H + soct*8;
        const __bf16* ag1 = xb  + (size_t)(row0 + (wid + 4)*16 + srow)*H + soct*8;
        const __bf16* bg0 = Wpb + (size_t)(col0 + (wid    )*16 + srow)*H + soct*8;
        const __bf16* bg1 = Wpb + (size_t)(col0 + (wid + 4)*16 + srow)*H + soct*8;
        const int lA0 = (wid    )*512, lA1 = (wid + 4)*512;
        const int lB0 = 4096 + (wid    )*512, lB1 = 4096 + (wid + 4)*512;

        f32x4 acc[4][4] = {};
        {   // prologue stage tile 0
            gld_lds16(ag0, lds + lA0); gld_lds16(ag1, lds + lA1);
            gld_lds16(bg0, lds + lB0); gld_lds16(bg1, lds + lB1);
            ag0 += 32; ag1 += 32; bg0 += 32; bg1 += 32;
        }
#pragma unroll 2
        for (int kt = 0; kt < 32; ++kt) {
            __syncthreads();
            if (kt + 1 < 32) {
                __bf16* base = lds + ((kt+1)&1)*8192;
                gld_lds16(ag0, base + lA0); gld_lds16(ag1, base + lA1);
                gld_lds16(bg0, base + lB0); gld_lds16(bg1, base + lB1);
                ag0 += 32; ag1 += 32; bg0 += 32; bg1 += 32;
            }
            mfma_tile(lds + (kt&1)*8192, aoff, boff, acc);
        }

        const int colb = (col0 & 1023) + wc + l15;
        const int rowb = row0 + wr + quad*4;
        const int seg  = col0 >> 10;
        if (seg == 0) {
            // delta: bias + softplus + store + per-32-row-chunk col sums.
            const int c0 = (row0 + wr) >> 5;        // rows wr..wr+31
#pragma unroll
            for (int j = 0; j < 4; ++j) {
                const int col = colb + j*16;
                const float bv = bd[col];
                float slo = 0.f, shi = 0.f;
#pragma unroll
                for (int i = 0; i < 4; ++i) {
                    float part = 0.f;
#pragma unroll
                    for (int r = 0; r < 4; ++r) {
                        float f = softplus_fast(acc[i][j][r] + bv);
                        db[(size_t)(rowb + i*16 + r) * H + col] = (__bf16)f;
                        part += f;
                    }
                    if (i < 2) slo += part; else shi += part;
                }
                slo += __shfl_down(slo, 32); slo += __shfl_down(slo, 16);
                shi += __shfl_down(shi, 32); shi += __shfl_down(shi, 16);
                if (quad == 0) {
                    pD[c0*H + col]     = slo;       // single writer
                    pD[(c0+1)*H + col] = shi;
                }
            }
        } else if (seg == 1) {
            // Cs: tile -> LDS [128][136], vectorized uC/Csum partials.
            __syncthreads();
#pragma unroll
            for (int i = 0; i < 4; ++i)
#pragma unroll
                for (int j = 0; j < 4; ++j) {
                    const int lrow0 = wr + quad*4 + i*16;
                    const int lcol  = wc + j*16 + l15;
#pragma unroll
                    for (int r = 0; r < 4; ++r)
                        lds[(lrow0 + r)*136 + lcol] = (__bf16)acc[i][j][r];
                }
            __syncthreads();
            const int g   = tid >> 4;
            const int oct = tid & 15;
            const int gc0 = (col0 & 1023) + oct*8;
            float su[8] = {}, sc[8] = {};
#pragma unroll
            for (int rr = 0; rr < 8; ++rr) {
                const int lrow = g*8 + rr;
                bf16x8 cv = *(const bf16x8*)(lds + lrow*136 + oct*8);
                bf16x8 xv = *(const bf16x8*)(xb + (size_t)(row0 + lrow)*H + gc0);
#pragma unroll
                for (int q = 0; q < 8; ++q) {
                    float c = (float)cv[q];
                    su[q] += (float)xv[q] * c;
                    sc[q] += c;
                }
            }
            float* pf = reinterpret_cast<float*>(lds);
            __syncthreads();
#pragma unroll
            for (int q = 0; q < 8; ++q) {
                pf[g*128 + oct*8 + q]        = su[q];
                pf[2048 + g*128 + oct*8 + q] = sc[q];
            }
            __syncthreads();
            const int col = tid & 127;
            const int rb  = row0 >> 7;
            float s = 0.f;
            if (tid < 128) {
#pragma unroll
                for (int g2 = 0; g2 < 16; ++g2) s += pf[g2*128 + col];
                pUp[rb*H + (col0 & 1023) + col] = s;
            } else {
#pragma unroll
                for (int g2 = 0; g2 < 16; ++g2) s += pf[2048 + g2*128 + col];
                pCp[rb*H + (col0 & 1023) + col] = s;
            }
        } else {
            // residual: plain store.
#pragma unroll
            for (int i = 0; i < 4; ++i)
#pragma unroll
                for (int j = 0; j < 4; ++j) {
                    const int col = colb + j*16;
#pragma unroll
                    for (int r = 0; r < 4; ++r)
                        resb[(size_t)(rowb + i*16 + r) * H + col] = (__bf16)acc[i][j][r];
                }
        }
    }

    grid_bar(cnt, 2u * NBLK);

    // ================= Phase 2: final combine ===============================
    {
        const int b = bid >> 7;            // 0..3
        const int rest = bid & 127;
        const int c = rest >> 1;           // 0..63 (32-row chunk)
        const int y = rest & 1;
        const int h0 = y*512 + tid*2;
        float run0 = 0.f, run1 = 0.f;
        for (int cp = 0; cp < c; ++cp) {
            f32x2 v = *(const f32x2*)(pD + (b*NCH + cp)*H + h0);
            run0 += v[0]; run1 += v[1];
        }
        float uc0 = 0.f, uc1 = 0.f, cs0 = 0.f, cs1 = 0.f;
#pragma unroll
        for (int i = 0; i < 16; ++i) {
            f32x2 u = *(const f32x2*)(pUp + (b*16 + i)*H + h0);
            f32x2 s = *(const f32x2*)(pCp + (b*16 + i)*H + h0);
            uc0 += u[0]; uc1 += u[1]; cs0 += s[0]; cs1 += s[1];
        }
        const f32x2 a1 = *(const f32x2*)(Av + h0);
        const f32x2 b1 = *(const f32x2*)(Bv + h0);
        const float dd = Dv[0];
        size_t base = ((size_t)(b*LSEQ + c*LCH)) * H + h0;
        for (int l = 0; l < LCH; ++l) {
            size_t idx = base + (size_t)l * H;
            bf16x2 dv2 = *(const bf16x2*)(db + idx);
            bf16x2 rs2 = *(const bf16x2*)(resb + idx);
            float d0 = (float)dv2[0], d1v = (float)dv2[1];
            run0 += d0; run1 += d1v;
            f32x2 o;
            o[0] = __expf(d0*a1[0])*b1[0]*uc0 + run0*b1[0]*cs0 + (float)rs2[0]*dd;
            o[1] = __expf(d1v*a1[1])*b1[1]*uc1 + run1*b1[1]*cs1 + (float)rs2[1]*dd;
            *(f32x2*)(out + idx) = o;
        }
    }
}

extern "C" void kernel_launch(void* const* d_in, const int* in_sizes, int n_in,
                              void* d_out, int out_size, void* d_ws, size_t ws_size,
                              hipStream_t stream)
{
    (void)in_sizes; (void)n_in; (void)out_size; (void)ws_size;
    const float* x  = (const float*)d_in[0];
    const float* Wp = (const float*)d_in[1];
    const float* Av = (const float*)d_in[2];
    const float* Bv = (const float*)d_in[3];
    const float* Dv = (const float*)d_in[4];
    const float* Wd = (const float*)d_in[5];
    const float* bd = (const float*)d_in[6];
    float* out = (float*)d_out;

    char* ws = (char*)d_ws;
    size_t o = 0;
    auto alloc = [&](size_t bytes) {
        void* p = ws + o; o += (bytes + 255) & ~(size_t)255; return p;
    };
    __bf16* xb   = (__bf16*)alloc((size_t)M_TOT * H * 2);
    __bf16* Wpb  = (__bf16*)alloc((size_t)3072 * H * 2);   // row0-1023 = Wfuse
    __bf16* resb = (__bf16*)alloc((size_t)M_TOT * H * 2);
    __bf16* db   = (__bf16*)alloc((size_t)M_TOT * H * 2);
    float*  pD   = (float*)alloc((size_t)BSZ * NCH * H * 4);
    float*  pUp  = (float*)alloc((size_t)64 * H * 4);
    float*  pCp  = (float*)alloc((size_t)64 * H * 4);
    unsigned* cnt = (unsigned*)alloc(256);

    (void)hipMemsetAsync(cnt, 0, 256, stream);
    fused<<<NBLK, 256, 0, stream>>>(x, Wp, Av, Bv, Dv, Wd, bd,
                                    xb, Wpb, resb, db, pD, pUp, pCp, cnt,
                                    out);
}